// Round 15
// baseline (380.643 us; speedup 1.0000x reference)
//
#include <hip/hip_runtime.h>
#include <hip/hip_bf16.h>

// Problem constants (B,S,E,H,L,DFF) = (2,2048,512,8,2,2048), D=64
constexpr int BB   = 2;
constexpr int SS   = 2048;
constexpr int EE   = 512;
constexpr int HH   = 8;
constexpr int DD   = 64;
constexpr int DFF_ = 2048;
constexpr int NTOK = BB * SS;          // 4096 tokens
constexpr int NE   = NTOK * EE;        // 2097152
constexpr float EPSF  = 1e-5f;
constexpr float SCL2  = 0.125f * 1.44269504088896f;  // 1/sqrt(D) * log2(e)
constexpr float MBIAS = -1e30f;
constexpr int KSPLIT = 2;              // attention split-K parts (R9/R12-proven)
constexpr int KHALF  = SS / KSPLIT;    // 1024

typedef __bf16 v8bf __attribute__((ext_vector_type(8)));
typedef __bf16 v4bf __attribute__((ext_vector_type(4)));
typedef float  v4f  __attribute__((ext_vector_type(4)));

__device__ __forceinline__ float bf2f(unsigned short u) {
    return __uint_as_float(((unsigned int)u) << 16);
}
__device__ __forceinline__ float bf2f(__bf16 u) {
    unsigned short us = __builtin_bit_cast(unsigned short, u);
    return __uint_as_float(((unsigned int)us) << 16);
}
// adaptive load: f=1 -> float32 buffer, f=0 -> bf16 buffer
__device__ __forceinline__ float ldA(const void* p, size_t i, int f) {
    return f ? ((const float*)p)[i] : bf2f(((const unsigned short*)p)[i]);
}
// async global->LDS, 16 B per lane (m97-verified path)
__device__ __forceinline__ void gll16(const void* g, void* l) {
    __builtin_amdgcn_global_load_lds(
        (const __attribute__((address_space(1))) void*)g,
        (__attribute__((address_space(3))) void*)l, 16, 0, 0);
}
// in-wave butterfly sum (all 64 lanes get total)
__device__ __forceinline__ float wsum(float v) {
    #pragma unroll
    for (int off = 1; off < 64; off <<= 1) v += __shfl_xor(v, off, 64);
    return v;
}

// --------------------------------------------------------------- dtype sniff
__global__ void sniff_kernel(const unsigned short* __restrict__ x, int* flag) {
    __shared__ int cnt[256];
    int t = threadIdx.x, bad = 0;
    for (int i = t; i < 4096; i += 256) {
        float v = bf2f(x[i]);
        if (!(fabsf(v) < 1000.f)) bad++;
    }
    cnt[t] = bad;
    __syncthreads();
    if (t == 0) {
        int s = 0;
        for (int i = 0; i < 256; ++i) s += cnt[i];
        *flag = (s > 8) ? 1 : 0;           // 1 = inputs are float32
    }
}

// --------------------------------------------------------------- all weights -> bf16 (one launch)
__global__ void wcvt_all(const void* __restrict__ wq, const void* __restrict__ wk,
                         const void* __restrict__ wv, const void* __restrict__ W1,
                         const void* __restrict__ W2, __bf16* __restrict__ out,
                         const int* __restrict__ flagp) {
    const int f = *flagp;
    const int i = (blockIdx.x * blockDim.x + threadIdx.x) * 8;
    constexpr int n1 = 2 * EE * EE;      // 524288 per QKV tensor
    constexpr int nf = DFF_ * EE;        // 1048576 per FFN tensor
    const void* src; int off;
    if      (i < n1)          { src = wq; off = i; }
    else if (i < 2 * n1)      { src = wk; off = i - n1; }
    else if (i < 3 * n1)      { src = wv; off = i - 2 * n1; }
    else if (i < 3 * n1 + nf) { src = W1; off = i - 3 * n1; }
    else                      { src = W2; off = i - 3 * n1 - nf; }
    if (f) {
        const float* p = (const float*)src + off;
        #pragma unroll
        for (int j = 0; j < 8; ++j) out[i + j] = (__bf16)p[j];
    } else {
        *(uint4*)(out + i) = *(const uint4*)((const unsigned short*)src + off);
    }
}

// --------------------------------------------------------------- wave-per-row LN (first layer)
// Reads raw x (adaptive dtype), writes X (f32 copy) AND Hb = LN(x,g1,b1) bf16.
// One wave per row: 8 elems/lane, butterfly reduce, no barriers/LDS.
__global__ __launch_bounds__(256) void ln_first(
    const void* __restrict__ xin, const void* __restrict__ g,
    const void* __restrict__ b, float* __restrict__ X,
    __bf16* __restrict__ Hb, const int* __restrict__ flagp)
{
    const int f = *flagp;
    const int wv = threadIdx.x >> 6, lane = threadIdx.x & 63;
    const int row = blockIdx.x * 4 + wv;
    const size_t base = (size_t)row * EE + lane * 8;
    float v[8];
    if (f) {
        float4 a0 = *(const float4*)((const float*)xin + base);
        float4 a1 = *(const float4*)((const float*)xin + base + 4);
        v[0]=a0.x; v[1]=a0.y; v[2]=a0.z; v[3]=a0.w;
        v[4]=a1.x; v[5]=a1.y; v[6]=a1.z; v[7]=a1.w;
    } else {
        v8bf u = *(const v8bf*)((const __bf16*)xin + base);
        #pragma unroll
        for (int j = 0; j < 8; ++j) v[j] = bf2f(u[j]);
    }
    // write X (f32 residual base)
    *(float4*)(X + base)     = make_float4(v[0], v[1], v[2], v[3]);
    *(float4*)(X + base + 4) = make_float4(v[4], v[5], v[6], v[7]);
    float s = 0.f, q = 0.f;
    #pragma unroll
    for (int j = 0; j < 8; ++j) { s += v[j]; q += v[j] * v[j]; }
    s = wsum(s); q = wsum(q);
    const float mu = s / EE, rs = rsqrtf(q / EE - mu * mu + EPSF);
    v8bf o;
    #pragma unroll
    for (int j = 0; j < 8; ++j) {
        float t_ = (v[j] - mu) * rs * ldA(g, lane * 8 + j, f) + ldA(b, lane * 8 + j, f);
        o[j] = (__bf16)t_;
    }
    *(v8bf*)(Hb + base) = o;
}

// --------------------------------------------------------------- wave-per-row LN (general)
// src f32. dstb: bf16 LN out (affine if g). outp: final output (dtype per flag).
__global__ __launch_bounds__(256) void ln_row(
    const float* __restrict__ src, const void* __restrict__ g,
    const void* __restrict__ b, __bf16* __restrict__ dstb,
    void* __restrict__ outp, const int* __restrict__ flagp)
{
    const int f = *flagp;
    const int wv = threadIdx.x >> 6, lane = threadIdx.x & 63;
    const int row = blockIdx.x * 4 + wv;
    const size_t base = (size_t)row * EE + lane * 8;
    float4 a0 = *(const float4*)(src + base);
    float4 a1 = *(const float4*)(src + base + 4);
    float v[8] = {a0.x, a0.y, a0.z, a0.w, a1.x, a1.y, a1.z, a1.w};
    float s = 0.f, q = 0.f;
    #pragma unroll
    for (int j = 0; j < 8; ++j) { s += v[j]; q += v[j] * v[j]; }
    s = wsum(s); q = wsum(q);
    const float mu = s / EE, rs = rsqrtf(q / EE - mu * mu + EPSF);
    float o[8];
    #pragma unroll
    for (int j = 0; j < 8; ++j) {
        o[j] = (v[j] - mu) * rs;
        if (g) o[j] = o[j] * ldA(g, lane * 8 + j, f) + ldA(b, lane * 8 + j, f);
    }
    if (dstb) {
        v8bf u;
        #pragma unroll
        for (int j = 0; j < 8; ++j) u[j] = (__bf16)o[j];
        *(v8bf*)(dstb + base) = u;
    }
    if (outp) {
        if (f) {
            *(float4*)((float*)outp + base)     = make_float4(o[0], o[1], o[2], o[3]);
            *(float4*)((float*)outp + base + 4) = make_float4(o[4], o[5], o[6], o[7]);
        } else {
            v8bf u;
            #pragma unroll
            for (int j = 0; j < 8; ++j) u[j] = (__bf16)o[j];
            *(v8bf*)((__bf16*)outp + base) = u;
        }
    }
}

// --------------------------------------------------------------- wave-per-row combine + residual + double LN
// Merges KSPLIT attention partials; x += LN(att,g2,b2); Hb = LN_noaffine(x).
// One wave per token. Lane owns c = lane*8..lane*8+7 = h*64+d0.. (h=lane>>3).
__global__ __launch_bounds__(256) void combine_row(
    const __bf16* __restrict__ Opart, const float* __restrict__ MLl,
    const void* __restrict__ g2, const void* __restrict__ b2,
    float* __restrict__ X, __bf16* __restrict__ Hb,
    const int* __restrict__ flagp)
{
    const int f = *flagp;
    const int wv = threadIdx.x >> 6, lane = threadIdx.x & 63;
    const int tok = blockIdx.x * 4 + wv;
    const int b_ = tok >> 11, s_ = tok & 2047;
    const int h = lane >> 3, d0 = (lane & 7) * 8;
    float l = 0.f;
    #pragma unroll
    for (int zz = 0; zz < KSPLIT; ++zz)
        l += MLl[(size_t)(zz * 16 + b_ * 8 + h) * SS + s_];
    const float cinv = (l > 0.f) ? 1.f / l : 0.f;
    float a[8] = {};
    #pragma unroll
    for (int zz = 0; zz < KSPLIT; ++zz) {
        const __bf16* p = Opart + ((size_t)(zz * 16 + b_ * 8 + h) * SS + s_) * 64 + d0;
        v8bf u = *(const v8bf*)p;
        #pragma unroll
        for (int j = 0; j < 8; ++j) a[j] += bf2f(u[j]);
    }
    #pragma unroll
    for (int j = 0; j < 8; ++j) a[j] *= cinv;
    // LN1 stats of attention-out row
    float s = 0.f, q = 0.f;
    #pragma unroll
    for (int j = 0; j < 8; ++j) { s += a[j]; q += a[j] * a[j]; }
    s = wsum(s); q = wsum(q);
    const float mu1 = s / EE, rs1 = rsqrtf(q / EE - mu1 * mu1 + EPSF);
    const size_t base = (size_t)tok * EE + lane * 8;
    float4 x0 = *(const float4*)(X + base);
    float4 x1 = *(const float4*)(X + base + 4);
    float xv[8] = {x0.x, x0.y, x0.z, x0.w, x1.x, x1.y, x1.z, x1.w};
    #pragma unroll
    for (int j = 0; j < 8; ++j)
        xv[j] += (a[j] - mu1) * rs1 * ldA(g2, lane * 8 + j, f) + ldA(b2, lane * 8 + j, f);
    // LN2 (noaffine) stats of new x row
    float s2 = 0.f, q2 = 0.f;
    #pragma unroll
    for (int j = 0; j < 8; ++j) { s2 += xv[j]; q2 += xv[j] * xv[j]; }
    s2 = wsum(s2); q2 = wsum(q2);
    const float mu2 = s2 / EE, rs2 = rsqrtf(q2 / EE - mu2 * mu2 + EPSF);
    *(float4*)(X + base)     = make_float4(xv[0], xv[1], xv[2], xv[3]);
    *(float4*)(X + base + 4) = make_float4(xv[4], xv[5], xv[6], xv[7]);
    v8bf u;
    #pragma unroll
    for (int j = 0; j < 8; ++j) u[j] = (__bf16)((xv[j] - mu2) * rs2);
    *(v8bf*)(Hb + base) = u;
}

// --------------------------------------------------------------- MFMA GEMM (NT), 128x128, double-buffered
// (R12-proven; 0.5 ds_read/MFMA)
__global__ __launch_bounds__(256) void gemm_mfma(
    const __bf16* __restrict__ A,
    const __bf16* Wa, const __bf16* Wb, const __bf16* Wc,
    const void* ba, const void* bb, const void* bc,
    __bf16* oa, __bf16* ob, __bf16* oc,
    float* __restrict__ Cf,
    int M, int N, int K, int flags,
    size_t welem_off, size_t belem_off, const int* __restrict__ flagp)
{
    const int f = *flagp;
    const int z = blockIdx.z;
    const __bf16* W = (z == 0) ? Wa : (z == 1) ? Wb : Wc;
    const void* bias = (z == 0) ? ba : (z == 1) ? bb : bc;
    __bf16* Cb = (z == 0) ? oa : (z == 1) ? ob : oc;
    W += welem_off;
    int kbeg = 0, kend = K;
    if (flags & 4) {
        const int ks = K >> 2;
        kbeg = z * ks; kend = kbeg + ks;
        if (z != 0) bias = nullptr;
    }

    __shared__ __bf16 As[2][128 * 32];   // 2 x 8 KB
    __shared__ __bf16 Bs[2][128 * 32];   // 2 x 8 KB
    const int t = threadIdx.x;
    const int w = t >> 6, lane = t & 63;
    const int quad = lane >> 4, l16 = lane & 15;
    const int wr = w >> 1, wc = w & 1;
    const int bm = blockIdx.x * 128, bn = blockIdx.y * 128;

    v4f acc[4][4] = {};
    const int c0 = t, c1 = t + 256;          // 512 16B chunks per tile
    const int r0 = c0 >> 2, e0 = (c0 & 3) * 8;
    const int r1 = c1 >> 2, e1 = (c1 & 3) * 8;

    // stage tile kbeg into buffer 0
    gll16(A + (size_t)(bm + r0) * K + kbeg + e0, (char*)As[0] + c0 * 16);
    gll16(A + (size_t)(bm + r1) * K + kbeg + e1, (char*)As[0] + c1 * 16);
    gll16(W + (size_t)(bn + r0) * K + kbeg + e0, (char*)Bs[0] + c0 * 16);
    gll16(W + (size_t)(bn + r1) * K + kbeg + e1, (char*)Bs[0] + c1 * 16);

    int p = 0;
    for (int k0 = kbeg; k0 < kend; k0 += 32) {
        __syncthreads();   // tile p staged (vmcnt drained at barrier); p^1 reads done
        if (k0 + 32 < kend) {
            const int kn = k0 + 32, q_ = p ^ 1;
            gll16(A + (size_t)(bm + r0) * K + kn + e0, (char*)As[q_] + c0 * 16);
            gll16(A + (size_t)(bm + r1) * K + kn + e1, (char*)As[q_] + c1 * 16);
            gll16(W + (size_t)(bn + r0) * K + kn + e0, (char*)Bs[q_] + c0 * 16);
            gll16(W + (size_t)(bn + r1) * K + kn + e1, (char*)Bs[q_] + c1 * 16);
        }
        v8bf af[4], bfr[4];
        #pragma unroll
        for (int i = 0; i < 4; ++i) {
            int row = wr * 64 + i * 16 + l16;
            af[i] = *(const v8bf*)&As[p][row * 32 + quad * 8];
        }
        #pragma unroll
        for (int j = 0; j < 4; ++j) {
            int row = wc * 64 + j * 16 + l16;
            bfr[j] = *(const v8bf*)&Bs[p][row * 32 + quad * 8];
        }
        #pragma unroll
        for (int i = 0; i < 4; ++i)
            #pragma unroll
            for (int j = 0; j < 4; ++j)
                acc[i][j] = __builtin_amdgcn_mfma_f32_16x16x32_bf16(
                    af[i], bfr[j], acc[i][j], 0, 0, 0);
        p ^= 1;
    }

    float bvv[4];
    #pragma unroll
    for (int j = 0; j < 4; ++j) {
        int col = bn + wc * 64 + j * 16 + l16;
        bvv[j] = bias ? ldA(bias, belem_off + col, f) : 0.f;
    }

    if ((flags & 8) && z == 2) {
        // V^T write with per-64-block s-permutation:
        // slot(s) = (s&32) + ((s>>2)&3)*8 + ((s>>4)&1)*4 + (s&3); r adds to low bits.
        #pragma unroll
        for (int i = 0; i < 4; ++i) {
            const int row0 = bm + wr * 64 + i * 16 + quad * 4;  // token (r=0)
            const int b_ = row0 >> 11, sl = row0 & 2047;
            const int s64 = sl & ~63, sloc = sl & 63;
            const int slot = (sloc & 32) + ((sloc >> 2) & 3) * 8 + ((sloc >> 4) & 1) * 4;
            #pragma unroll
            for (int j = 0; j < 4; ++j) {
                const int col = bn + wc * 64 + j * 16 + l16;
                const int h_ = col >> 6, d_ = col & 63;
                v4bf u;
                #pragma unroll
                for (int r = 0; r < 4; ++r) u[r] = (__bf16)(acc[i][j][r] + bvv[j]);
                *(v4bf*)(Cb + ((size_t)((b_ * 8 + h_) * 64 + d_)) * SS + s64 + slot) = u;
            }
        }
        return;
    }

    #pragma unroll
    for (int i = 0; i < 4; ++i) {
        const int rowb = bm + wr * 64 + i * 16 + quad * 4;
        #pragma unroll
        for (int j = 0; j < 4; ++j) {
            const int col = bn + wc * 64 + j * 16 + l16;
            #pragma unroll
            for (int r = 0; r < 4; ++r) {
                float v = acc[i][j][r] + bvv[j];
                if (flags & 1) v = fmaxf(v, 0.f);
                const size_t idx = (size_t)(rowb + r) * N + col;
                if (flags & 4)      unsafeAtomicAdd(&Cf[idx], v);
                else if (flags & 2) Cf[idx] += v;
                else                Cb[idx] = (__bf16)v;
            }
        }
    }
}

// --------------------------------------------------------------- MFMA attention (AQ=128, 8 waves)
// Transposed dataflow (S^T = K*Q^T), split-K x2, no max-tracking, PERMUTED-V.
// 512-thread blocks: 8 waves share each staged K/V tile (R14-proven).
__global__ __launch_bounds__(512) void attn_mfma(
    const __bf16* __restrict__ Qg, const __bf16* __restrict__ Kg,
    const __bf16* __restrict__ Vtg, const int* __restrict__ mask,
    __bf16* __restrict__ Opart, float* __restrict__ MLl)
{
    __shared__ __bf16 Ks[64][72];     // [token][d]  (true s order)
    __shared__ __bf16 Vs[64][72];     // [d][slot]   (permuted s)
    __shared__ float  mkf[64];

    const int t = threadIdx.x;
    const int w = t >> 6, lane = t & 63;      // w in 0..7
    const int quad = lane >> 4, l16 = lane & 15;
    const int bh = blockIdx.y, b = bh >> 3, h = bh & 7;
    const int q0 = blockIdx.x * 128;
    const int z  = blockIdx.z;
    const int kof = z * KHALF;

    // Q fragments (B-operand of S^T: n=l16 -> q-row, k=quad*8+j -> d)
    const __bf16* qrow = Qg + ((size_t)(b * SS + q0 + w * 16 + l16)) * EE + h * DD + quad * 8;
    const v8bf qa0 = *(const v8bf*)qrow;
    const v8bf qa1 = *(const v8bf*)(qrow + 32);

    // loader mapping: 512 threads, one v8bf each: row lr (0..63), chunk lc
    const int lr = t >> 3, lc = (t & 7) * 8;
    const __bf16* kbase = Kg  + ((size_t)(b * SS + kof + lr)) * EE + h * DD + lc;
    const __bf16* vbase = Vtg + ((size_t)((b * 8 + h) * 64 + lr)) * SS + kof + lc;

    // prefetch tile 0
    v8bf ka = *(const v8bf*)kbase;
    v8bf va = *(const v8bf*)vbase;
    float mb = 0.f;
    if (t < 64) mb = mask[b * SS + kof + t] ? MBIAS : 0.f;

    float l_acc = 0.f;
    v4f o[4] = {};

    #pragma unroll 1
    for (int k0 = 0; k0 < KHALF; k0 += 64) {
        *(v8bf*)&Ks[lr][lc] = ka;
        *(v8bf*)&Vs[lr][lc] = va;
        if (t < 64) mkf[t] = mb;
        __syncthreads();
        if (k0 + 64 < KHALF) {   // prefetch next tile
            ka = *(const v8bf*)(kbase + (size_t)(k0 + 64) * EE);
            va = *(const v8bf*)(vbase + (k0 + 64));
            if (t < 64) mb = mask[b * SS + kof + k0 + 64 + t] ? MBIAS : 0.f;
        }

        // ---- S^T = K*Q^T : s4[j] holds true s = j*16+quad*4+r, q = l16
        v4f s4[4];
        #pragma unroll
        for (int j = 0; j < 4; ++j) {
            v8bf kf0 = *(const v8bf*)&Ks[j * 16 + l16][quad * 8];
            v8bf kf1 = *(const v8bf*)&Ks[j * 16 + l16][32 + quad * 8];
            v4f zz = {};
            zz = __builtin_amdgcn_mfma_f32_16x16x32_bf16(kf0, qa0, zz, 0, 0, 0);
            zz = __builtin_amdgcn_mfma_f32_16x16x32_bf16(kf1, qa1, zz, 0, 0, 0);
            s4[j] = zz;
        }
        float4 mk4[4];
        #pragma unroll
        for (int j = 0; j < 4; ++j) mk4[j] = *(const float4*)&mkf[j * 16 + quad * 4];

        // ---- p = exp2(s*scl + maskbias); pack DIRECTLY into PV B-operands
        v8bf pb0, pb1;
        float ts = 0.f;
        #pragma unroll
        for (int j = 0; j < 4; ++j) {
            float p0 = exp2f(fmaf(s4[j][0], SCL2, mk4[j].x));
            float p1 = exp2f(fmaf(s4[j][1], SCL2, mk4[j].y));
            float p2 = exp2f(fmaf(s4[j][2], SCL2, mk4[j].z));
            float p3 = exp2f(fmaf(s4[j][3], SCL2, mk4[j].w));
            ts += (p0 + p1) + (p2 + p3);
            if (j < 2) {
                pb0[j * 4 + 0] = (__bf16)p0; pb0[j * 4 + 1] = (__bf16)p1;
                pb0[j * 4 + 2] = (__bf16)p2; pb0[j * 4 + 3] = (__bf16)p3;
            } else {
                pb1[(j - 2) * 4 + 0] = (__bf16)p0; pb1[(j - 2) * 4 + 1] = (__bf16)p1;
                pb1[(j - 2) * 4 + 2] = (__bf16)p2; pb1[(j - 2) * 4 + 3] = (__bf16)p3;
            }
        }
        l_acc += ts;

        // ---- O^T += V^T * P^T : A=V^T (m=d, k=slot), B=P (k=slot, n=q=l16)
        #pragma unroll
        for (int dt = 0; dt < 4; ++dt) {
            v8bf vf0 = *(const v8bf*)&Vs[dt * 16 + l16][quad * 8];
            v8bf vf1 = *(const v8bf*)&Vs[dt * 16 + l16][32 + quad * 8];
            o[dt] = __builtin_amdgcn_mfma_f32_16x16x32_bf16(vf0, pb0, o[dt], 0, 0, 0);
            o[dt] = __builtin_amdgcn_mfma_f32_16x16x32_bf16(vf1, pb1, o[dt], 0, 0, 0);
        }
        __syncthreads();   // readers done before next restage
    }

    // row totals: sum l over the 4 quads holding this q-row
    l_acc += __shfl_xor(l_acc, 16, 64);
    l_acc += __shfl_xor(l_acc, 32, 64);

    // ---- epilogue: raw partial O^T (col=l16 -> q; row=quad*4+r -> d)
    const size_t qi = (size_t)(z * 16 + bh) * SS + (q0 + w * 16 + l16);
    __bf16* op = Opart + qi * 64;
    #pragma unroll
    for (int dt = 0; dt < 4; ++dt) {
        v4bf u;
        #pragma unroll
        for (int r = 0; r < 4; ++r) u[r] = (__bf16)o[dt][r];
        *(v4bf*)(op + dt * 16 + quad * 4) = u;
    }
    if (quad == 0) MLl[qi] = l_acc;
}

// --------------------------------------------------------------- launch
extern "C" void kernel_launch(void* const* d_in, const int* in_sizes, int n_in,
                              void* d_out, int out_size, void* d_ws, size_t ws_size,
                              hipStream_t stream) {
    const void* x_in = d_in[0];
    const int*  mask = (const int*)d_in[1];
    const void* wq = d_in[2];  const void* bq = d_in[3];
    const void* wk = d_in[4];  const void* bk = d_in[5];
    const void* wv = d_in[6];  const void* bv = d_in[7];
    const void* g1 = d_in[8];  const void* b1 = d_in[9];
    const void* g2 = d_in[10]; const void* b2 = d_in[11];
    const void* gf = d_in[12]; const void* bfp= d_in[13];
    const void* W1 = d_in[14]; const void* B1 = d_in[15];
    const void* W2 = d_in[16]; const void* B2 = d_in[17];

    // ws layout (float units), ~50 MB total:
    // X | Qb Kb Vtg Hb | weights | MLl | Opart/MID shared region (2*NE floats)
    float* base = (float*)d_ws;
    int*   flag = (int*)base;
    float* X   = base + 16;          // NE f32 residual (persistent)
    float* fQ  = X + NE;             // NE/2 floats (Qb)
    float* fK  = fQ + NE / 2;        // NE/2 floats (Kb)
    float* fV  = fK + NE / 2;        // NE/2 floats (Vt global, s-permuted)
    float* fH  = fV + NE / 2;        // NE/2 floats (Hb)
    float* fW  = fH + NE / 2;        // converted weights (contiguous)
    __bf16* Qb    = (__bf16*)fQ;
    __bf16* Kb    = (__bf16*)fK;
    __bf16* Vtg   = (__bf16*)fV;     // [ (b*8+h)*64 + d ][ s (permuted/64) ]
    __bf16* Hb    = (__bf16*)fH;
    __bf16* wqc = (__bf16*)fW;
    __bf16* wkc = wqc + 2 * EE * EE;
    __bf16* wvc = wkc + 2 * EE * EE;
    __bf16* W1c = wvc + 2 * EE * EE;
    __bf16* W2c = W1c + DFF_ * EE;
    float* MLl = (float*)(W2c + (size_t)EE * DFF_);   // KSPLIT*16*SS f32
    float* fO  = MLl + (size_t)KSPLIT * 16 * SS;
    __bf16* Opart = (__bf16*)fO;     // KSPLIT x 16 bh x 2048 x 64 bf16
    __bf16* MID   = (__bf16*)fO;     // NTOK*DFF bf16 (region sized for MID: 2*NE floats)

    sniff_kernel<<<1, 256, 0, stream>>>((const unsigned short*)x_in, flag);
    wcvt_all<<<1792, 256, 0, stream>>>(wq, wk, wv, W1, W2, wqc, flag);

    const dim3 gQKV(NTOK / 128, EE / 128, 3);      // 384 blocks
    const dim3 gF1 (NTOK / 128, DFF_ / 128, 1);    // 512 blocks
    const dim3 gF2 (NTOK / 128, EE / 128, 4);      // 512 blocks (split-K x4)
    const dim3 gAtt(SS / 128, BB * HH, KSPLIT);    // 512 blocks x 8 waves
    const int  gLN = NTOK / 4;                     // 1024 blocks, wave-per-row

    for (int l = 0; l < 2; ++l) {
        const size_t wo = (size_t)l * EE * EE, bo = (size_t)l * EE;
        // h = LN(x,g1,b1) -> bf16 (layer 0 also materializes X from raw x)
        if (l == 0)
            ln_first<<<gLN, 256, 0, stream>>>(x_in, g1, b1, X, Hb, flag);
        else
            ln_row<<<gLN, 256, 0, stream>>>(X, g1, b1, Hb, nullptr, flag);
        // q,k,v fused; z==2 writes permuted V^T (flags|8)
        gemm_mfma<<<gQKV, 256, 0, stream>>>(Hb, wqc, wkc, wvc, bq, bk, bv,
            Qb, Kb, Vtg, nullptr, NTOK, EE, EE, 8, wo, bo, flag);
        // attention partials (raw sums + l), 512-thread blocks
        attn_mfma<<<gAtt, 512, 0, stream>>>(Qb, Kb, Vtg, mask, Opart, MLl);
        // combine partials; x += LN(att,g2,b2); h = LN_noaffine(x)  (wave-per-token)
        combine_row<<<gLN, 256, 0, stream>>>(Opart, MLl, g2, b2, X, Hb, flag);
        // mid = relu(h @ W1^T + B1) -> bf16 (MID aliases dead Opart)
        gemm_mfma<<<gF1, 256, 0, stream>>>(Hb, W1c, W1c, W1c, B1, B1, B1,
            MID, MID, MID, nullptr, NTOK, DFF_, EE, 1, 0, 0, flag);
        // x += mid @ W2^T + B2  (split-K x4, atomic f32)
        gemm_mfma<<<gF2, 256, 0, stream>>>(MID, W2c, W2c, W2c, B2, B2, B2,
            nullptr, nullptr, nullptr, X, NTOK, EE, DFF_, 2 | 4, 0, 0, flag);
    }
    // out = LN(x, gf, bf)  (wave-per-row, adaptive output dtype)
    ln_row<<<gLN, 256, 0, stream>>>(X, gf, bfp, nullptr, d_out, flag);
}